// Round 1
// baseline (468.986 us; speedup 1.0000x reference)
//
#include <hip/hip_runtime.h>
#include <cstdint>
#include <cstddef>

typedef __bf16 bf16;
typedef __attribute__((ext_vector_type(8))) __bf16 bf16x8;
typedef __attribute__((ext_vector_type(4))) __bf16 bf16x4;
typedef __attribute__((ext_vector_type(4))) float f32x4;

constexpr int kS = 2048;
constexpr int kH = 16;
constexpr int kD = 64;

__device__ __forceinline__ void gload16(const bf16* g, bf16* l) {
  __builtin_amdgcn_global_load_lds((const __attribute__((address_space(1))) void*)g,
                                   (__attribute__((address_space(3))) void*)l, 16, 0, 0);
}

// ---------------- cast fp32 -> bf16 (x + 4 weights) ----------------
__global__ __launch_bounds__(256) void cast_all_kernel(
    const float* __restrict__ x, const float* __restrict__ wq, const float* __restrict__ wk,
    const float* __restrict__ wv, const float* __restrict__ wo,
    bf16* __restrict__ xb, bf16* __restrict__ wqb, bf16* __restrict__ wkb,
    bf16* __restrict__ wvb, bf16* __restrict__ wob) {
  int idx = blockIdx.x * 256 + threadIdx.x;   // 2M threads, 4 floats each
  const float* src; bf16* dst; int i;
  if (idx < (1 << 20)) { src = x; dst = xb; i = idx << 2; }
  else {
    int r = idx - (1 << 20);
    int t = r >> 18;
    i = (r & ((1 << 18) - 1)) << 2;
    src = (t == 0) ? wq : (t == 1) ? wk : (t == 2) ? wv : wo;
    dst = (t == 0) ? wqb : (t == 1) ? wkb : (t == 2) ? wvb : wob;
  }
  float4 v = *(const float4*)(src + i);
  bf16x4 o;
  o[0] = (bf16)v.x; o[1] = (bf16)v.y; o[2] = (bf16)v.z; o[3] = (bf16)v.w;
  *(bf16x4*)(dst + i) = o;
}

// ---------------- GEMM C[m][n] = sum_k A[m][k] * B[n][k] ----------------
// EPI 0: bf16 out scattered to [B,H,S,D]   (m=b*S+s, n=h*64+d)
// EPI 1: bf16 out scattered to [B,H,D,S]   (m=e=h*64+d, n=b*S+s)  [V^T compute]
// EPI 2: fp32 out plain [m][n]
template<int EPI>
__global__ __launch_bounds__(256) void gemm_bt(const bf16* __restrict__ A,
                                               const bf16* __restrict__ Bw,
                                               void* __restrict__ Cout,
                                               int M, int N, int K) {
  __shared__ bf16 As[128 * 32];
  __shared__ bf16 Bs[128 * 32];
  const int tid = threadIdx.x;
  const int w = tid >> 6, l = tid & 63;
  const int wr = w >> 1, wc = w & 1;
  const int lr = l & 15, lg = l >> 4;
  const int m0 = blockIdx.y * 128, n0 = blockIdx.x * 128;

  const int srow = l >> 2;            // 0..15 within a 16-row group
  const int skcol = (l & 3) << 3;     // 0,8,16,24

  const bf16* aP0 = A + (size_t)(m0 + w * 16 + srow) * K + skcol;
  const bf16* aP1 = A + (size_t)(m0 + 64 + w * 16 + srow) * K + skcol;
  const bf16* bP0 = Bw + (size_t)(n0 + w * 16 + srow) * K + skcol;
  const bf16* bP1 = Bw + (size_t)(n0 + 64 + w * 16 + srow) * K + skcol;
  bf16* aL0 = As + (w * 64 + l) * 8;
  bf16* aL1 = As + ((4 + w) * 64 + l) * 8;
  bf16* bL0 = Bs + (w * 64 + l) * 8;
  bf16* bL1 = Bs + ((4 + w) * 64 + l) * 8;

  f32x4 acc[4][4] = {};

  for (int kt = 0; kt < K; kt += 32) {
    gload16(aP0 + kt, aL0);
    gload16(aP1 + kt, aL1);
    gload16(bP0 + kt, bL0);
    gload16(bP1 + kt, bL1);
    __syncthreads();
    bf16x8 af[4], bfg[4];
#pragma unroll
    for (int mi = 0; mi < 4; mi++)
      af[mi] = *(const bf16x8*)&As[(wr * 64 + mi * 16 + lr) * 32 + lg * 8];
#pragma unroll
    for (int ni = 0; ni < 4; ni++)
      bfg[ni] = *(const bf16x8*)&Bs[(wc * 64 + ni * 16 + lr) * 32 + lg * 8];
#pragma unroll
    for (int mi = 0; mi < 4; mi++)
#pragma unroll
      for (int ni = 0; ni < 4; ni++)
        acc[mi][ni] = __builtin_amdgcn_mfma_f32_16x16x32_bf16(af[mi], bfg[ni], acc[mi][ni], 0, 0, 0);
    __syncthreads();
  }

#pragma unroll
  for (int mi = 0; mi < 4; mi++) {
#pragma unroll
    for (int ni = 0; ni < 4; ni++) {
#pragma unroll
      for (int r = 0; r < 4; r++) {
        const int m = m0 + wr * 64 + mi * 16 + lg * 4 + r;
        const int n = n0 + wc * 64 + ni * 16 + lr;
        const float v = acc[mi][ni][r];
        if (EPI == 0) {
          bf16* dst = (bf16*)Cout;
          dst[((((size_t)(m >> 11) * kH + (n >> 6)) << 11) + (m & 2047)) * kD + (n & 63)] = (bf16)v;
        } else if (EPI == 1) {
          bf16* dst = (bf16*)Cout;
          dst[((((size_t)(n >> 11) * kH + (m >> 6)) * kD + (m & 63)) << 11) + (n & 2047)] = (bf16)v;
        } else {
          float* dst = (float*)Cout;
          dst[(size_t)m * N + n] = v;
        }
      }
    }
  }
}

// ---------------- RoPE in-place on [B,H,S,D] bf16 (q then k) ----------------
__global__ __launch_bounds__(256) void rope_kernel(bf16* __restrict__ q, bf16* __restrict__ k) {
  int idx = blockIdx.x * 256 + threadIdx.x;        // 1M threads: 2 tensors x 512K groups of 8
  bf16* base = (idx < (1 << 19)) ? q : k;
  int gg = idx & ((1 << 19) - 1);
  int s = (gg >> 3) & 2047;
  int d0 = (gg & 7) << 3;
  bf16* p = base + (size_t)gg * 8;
  bf16x8 v = *(bf16x8*)p;
  bf16x8 o;
  const float nl = -9.210340371976184f / 32.0f;    // -ln(10000)/32
#pragma unroll
  for (int pr = 0; pr < 4; pr++) {
    int d = d0 + 2 * pr;
    float x0 = (float)v[2 * pr], x1 = (float)v[2 * pr + 1];
    float th0 = s * expf((float)(d & 31) * nl);
    float th1 = s * expf((float)((d + 1) & 31) * nl);
    float c0 = cosf(th0), s0 = sinf(th0);
    float c1 = cosf(th1), s1 = sinf(th1);
    o[2 * pr]     = (bf16)(x0 * c0 - x1 * s0);
    o[2 * pr + 1] = (bf16)(x1 * c1 + x0 * s1);
  }
  *(bf16x8*)p = o;
}

// ---------------- flash attention, causal ----------------
// q,k: [B,H,S,D] bf16 (rope'd). vt: [B,H,D,S] bf16. out: [B,S,E] bf16.
// 4 waves/block, wave = 16 q-rows. Swapped QK^T (S^T: col=q=lane&15).
// PV uses k-permutation pi(8g+4s+r)=16s+4g+r so the P fragment is exactly
// the registers each lane already holds (no shuffles); V fragment loaded
// with the matching permutation (two b64 loads).
__global__ __launch_bounds__(256) void attn_kernel(const bf16* __restrict__ qb,
                                                   const bf16* __restrict__ kb,
                                                   const bf16* __restrict__ vtb,
                                                   bf16* __restrict__ ob) {
  const int tid = threadIdx.x;
  const int w = tid >> 6, l = tid & 63;
  const int lr = l & 15, lg = l >> 4;
  const int bid = blockIdx.x;
  const int bh = bid >> 5;                  // 32 q-tiles of 64 per (b,h)
  const int qt = bid & 31;
  const int q0 = qt * 64 + w * 16;
  const bf16* qh = qb + (size_t)bh * (kS * kD);
  const bf16* kh = kb + (size_t)bh * (kS * kD);
  const bf16* vh = vtb + (size_t)bh * (kS * kD);
  const int b = bh >> 4, h = bh & 15;

  bf16x8 qf[2];
#pragma unroll
  for (int c = 0; c < 2; c++)
    qf[c] = *(const bf16x8*)&qh[(size_t)(q0 + lr) * kD + c * 32 + lg * 8];

  float m_run = -1e30f, l_run = 0.0f;
  f32x4 o[4] = {};
  const int q = q0 + lr;                    // this lane's q row (softmax state owner)
  const int ntiles = (q0 + 15) / 32 + 1;

  for (int t = 0; t < ntiles; t++) {
    const int kv0 = t * 32;
    f32x4 sa[2] = {};
#pragma unroll
    for (int s = 0; s < 2; s++) {
      bf16x8 kf0 = *(const bf16x8*)&kh[(size_t)(kv0 + s * 16 + lr) * kD + 0 * 32 + lg * 8];
      bf16x8 kf1 = *(const bf16x8*)&kh[(size_t)(kv0 + s * 16 + lr) * kD + 1 * 32 + lg * 8];
      sa[s] = __builtin_amdgcn_mfma_f32_16x16x32_bf16(kf0, qf[0], sa[s], 0, 0, 0);
      sa[s] = __builtin_amdgcn_mfma_f32_16x16x32_bf16(kf1, qf[1], sa[s], 0, 0, 0);
    }
    float p[2][4];
    float tm = -1e30f;
#pragma unroll
    for (int s = 0; s < 2; s++)
#pragma unroll
      for (int r = 0; r < 4; r++) {
        int kk = kv0 + s * 16 + lg * 4 + r;
        float v = sa[s][r] * 0.125f;
        v = (kk <= q) ? v : -1e30f;
        p[s][r] = v;
        tm = fmaxf(tm, v);
      }
    tm = fmaxf(tm, __shfl_xor(tm, 16));
    tm = fmaxf(tm, __shfl_xor(tm, 32));
    const float m_new = fmaxf(m_run, tm);
    const float f = __expf(m_run - m_new);
    float ts = 0.0f;
#pragma unroll
    for (int s = 0; s < 2; s++)
#pragma unroll
      for (int r = 0; r < 4; r++) {
        float e = __expf(p[s][r] - m_new);
        p[s][r] = e;
        ts += e;
      }
    ts += __shfl_xor(ts, 16);
    ts += __shfl_xor(ts, 32);
    l_run = l_run * f + ts;
    m_run = m_new;
#pragma unroll
    for (int c = 0; c < 4; c++) o[c] *= f;

    bf16x8 pf;
#pragma unroll
    for (int j = 0; j < 8; j++) pf[j] = (bf16)p[j >> 2][j & 3];

#pragma unroll
    for (int c = 0; c < 4; c++) {
      const bf16* vrow = &vh[(size_t)(c * 16 + lr) * kS + kv0 + lg * 4];
      bf16x4 v0 = *(const bf16x4*)vrow;
      bf16x4 v1 = *(const bf16x4*)(vrow + 16);
      bf16x8 af;
      af[0] = v0[0]; af[1] = v0[1]; af[2] = v0[2]; af[3] = v0[3];
      af[4] = v1[0]; af[5] = v1[1]; af[6] = v1[2]; af[7] = v1[3];
      o[c] = __builtin_amdgcn_mfma_f32_16x16x32_bf16(af, pf, o[c], 0, 0, 0);
    }
  }

  const float inv = 1.0f / l_run;
#pragma unroll
  for (int c = 0; c < 4; c++) {
    bf16x4 ov;
#pragma unroll
    for (int r = 0; r < 4; r++) ov[r] = (bf16)(o[c][r] * inv);
    size_t addr = ((size_t)(b * kS + q0 + lr)) * (kH * kD) + h * 64 + c * 16 + lg * 4;
    *(bf16x4*)&ob[addr] = ov;
  }
}

extern "C" void kernel_launch(void* const* d_in, const int* in_sizes, int n_in,
                              void* d_out, int out_size, void* d_ws, size_t ws_size,
                              hipStream_t stream) {
  const float* x  = (const float*)d_in[0];
  const float* wq = (const float*)d_in[1];
  const float* wk = (const float*)d_in[2];
  const float* wv = (const float*)d_in[3];
  const float* wo = (const float*)d_in[4];

  bf16* xb  = (bf16*)d_ws;            // 4M elems each (8 MiB)
  bf16* qb  = xb + (1 << 22);
  bf16* kb  = qb + (1 << 22);
  bf16* vtb = kb + (1 << 22);
  bf16* ab  = vtb + (1 << 22);
  bf16* wqb = ab + (1 << 22);         // 1M elems each (2 MiB)
  bf16* wkb = wqb + (1 << 20);
  bf16* wvb = wkb + (1 << 20);
  bf16* wob = wvb + (1 << 20);

  cast_all_kernel<<<8192, 256, 0, stream>>>(x, wq, wk, wv, wo, xb, wqb, wkb, wvb, wob);
  gemm_bt<0><<<dim3(8, 32), 256, 0, stream>>>(xb, wqb, (void*)qb, 4096, 1024, 1024);
  gemm_bt<0><<<dim3(8, 32), 256, 0, stream>>>(xb, wkb, (void*)kb, 4096, 1024, 1024);
  gemm_bt<1><<<dim3(32, 8), 256, 0, stream>>>(wvb, xb, (void*)vtb, 1024, 4096, 1024);
  rope_kernel<<<4096, 256, 0, stream>>>(qb, kb);
  attn_kernel<<<1024, 256, 0, stream>>>(qb, kb, vtb, ab);
  gemm_bt<2><<<dim3(8, 32), 256, 0, stream>>>(ab, wob, d_out, 4096, 1024, 1024);
}

// Round 3
// 315.098 us; speedup vs baseline: 1.4884x; 1.4884x over previous
//
#include <hip/hip_runtime.h>
#include <cstdint>
#include <cstddef>

typedef __bf16 bf16;
typedef __attribute__((ext_vector_type(8))) __bf16 bf16x8;
typedef __attribute__((ext_vector_type(4))) __bf16 bf16x4;
typedef __attribute__((ext_vector_type(4))) float f32x4;

constexpr int kS = 2048;
constexpr int kH = 16;
constexpr int kD = 64;

__device__ __forceinline__ void gload16(const bf16* g, bf16* l) {
  __builtin_amdgcn_global_load_lds((const __attribute__((address_space(1))) void*)g,
                                   (__attribute__((address_space(3))) void*)l, 16, 0, 0);
}

// ---------------- cast fp32 -> bf16 (x + 4 weights) ----------------
__global__ __launch_bounds__(256) void cast_all_kernel(
    const float* __restrict__ x, const float* __restrict__ wq, const float* __restrict__ wk,
    const float* __restrict__ wv, const float* __restrict__ wo,
    bf16* __restrict__ xb, bf16* __restrict__ wqb, bf16* __restrict__ wkb,
    bf16* __restrict__ wvb, bf16* __restrict__ wob) {
  int idx = blockIdx.x * 256 + threadIdx.x;   // 2M threads, 4 floats each
  const float* src; bf16* dst; int i;
  if (idx < (1 << 20)) { src = x; dst = xb; i = idx << 2; }
  else {
    int r = idx - (1 << 20);
    int t = r >> 18;
    i = (r & ((1 << 18) - 1)) << 2;
    src = (t == 0) ? wq : (t == 1) ? wk : (t == 2) ? wv : wo;
    dst = (t == 0) ? wqb : (t == 1) ? wkb : (t == 2) ? wvb : wob;
  }
  float4 v = *(const float4*)(src + i);
  bf16x4 o;
  o[0] = (bf16)v.x; o[1] = (bf16)v.y; o[2] = (bf16)v.z; o[3] = (bf16)v.w;
  *(bf16x4*)(dst + i) = o;
}

// ---------------- fused QKV GEMM ----------------
// C[m][n] = sum_k x[m][k] * W[n][k], W in {Wq,Wk,Wv} by n-region.
// q,k -> [B,H,S,D] bf16; v -> [B,H,D,S] bf16 (pre-transposed for attn PV).
__global__ __launch_bounds__(256) void gemm_qkv(const bf16* __restrict__ A,
                                                const bf16* __restrict__ wq,
                                                const bf16* __restrict__ wk,
                                                const bf16* __restrict__ wv,
                                                bf16* __restrict__ qo,
                                                bf16* __restrict__ ko,
                                                bf16* __restrict__ vto) {
  __shared__ bf16 As[128 * 32];
  __shared__ bf16 Bs[128 * 32];
  const int tid = threadIdx.x;
  const int w = tid >> 6, l = tid & 63;
  const int wr = w >> 1, wc = w & 1;
  const int lr = l & 15, lg = l >> 4;

  // XCD-aware remap of 768 blocks (768 % 8 == 0 -> bijective)
  const int fid = (blockIdx.x & 7) * 96 + (blockIdx.x >> 3);
  const int mblk = fid & 31;            // 0..31
  const int ntile = fid >> 5;           // 0..23
  const int which = ntile >> 3;         // 0=q 1=k 2=v
  const int m0 = mblk * 128;
  const int n0 = (ntile & 7) * 128;
  const bf16* Bw = (which == 0) ? wq : (which == 1) ? wk : wv;

  const int srow = l >> 2;
  const int skcol = (l & 3) << 3;
  const int K = 1024;

  const bf16* aP0 = A + (size_t)(m0 + w * 16 + srow) * K + skcol;
  const bf16* aP1 = A + (size_t)(m0 + 64 + w * 16 + srow) * K + skcol;
  const bf16* bP0 = Bw + (size_t)(n0 + w * 16 + srow) * K + skcol;
  const bf16* bP1 = Bw + (size_t)(n0 + 64 + w * 16 + srow) * K + skcol;
  bf16* aL0 = As + (w * 64 + l) * 8;
  bf16* aL1 = As + ((4 + w) * 64 + l) * 8;
  bf16* bL0 = Bs + (w * 64 + l) * 8;
  bf16* bL1 = Bs + ((4 + w) * 64 + l) * 8;

  f32x4 acc[4][4] = {};

  for (int kt = 0; kt < K; kt += 32) {
    gload16(aP0 + kt, aL0);
    gload16(aP1 + kt, aL1);
    gload16(bP0 + kt, bL0);
    gload16(bP1 + kt, bL1);
    __syncthreads();
    bf16x8 af[4], bfg[4];
#pragma unroll
    for (int mi = 0; mi < 4; mi++)
      af[mi] = *(const bf16x8*)&As[(wr * 64 + mi * 16 + lr) * 32 + lg * 8];
#pragma unroll
    for (int ni = 0; ni < 4; ni++)
      bfg[ni] = *(const bf16x8*)&Bs[(wc * 64 + ni * 16 + lr) * 32 + lg * 8];
#pragma unroll
    for (int mi = 0; mi < 4; mi++)
#pragma unroll
      for (int ni = 0; ni < 4; ni++)
        acc[mi][ni] = __builtin_amdgcn_mfma_f32_16x16x32_bf16(af[mi], bfg[ni], acc[mi][ni], 0, 0, 0);
    __syncthreads();
  }

#pragma unroll
  for (int mi = 0; mi < 4; mi++) {
#pragma unroll
    for (int ni = 0; ni < 4; ni++) {
#pragma unroll
      for (int r = 0; r < 4; r++) {
        const int m = m0 + wr * 64 + mi * 16 + lg * 4 + r;   // token index
        const int n = n0 + wc * 64 + ni * 16 + lr;           // emb index (h*64+d)
        const float v = acc[mi][ni][r];
        if (which < 2) {
          bf16* dst = which ? ko : qo;                       // [B,H,S,D]
          dst[((((size_t)(m >> 11) * kH + (n >> 6)) << 11) + (m & 2047)) * kD + (n & 63)] = (bf16)v;
        } else {                                             // [B,H,D,S]
          vto[((((size_t)(m >> 11) * kH + (n >> 6)) * kD + (n & 63)) << 11) + (m & 2047)] = (bf16)v;
        }
      }
    }
  }
}

// ---------------- final GEMM C = A @ Wo^T, fp32 out ----------------
__global__ __launch_bounds__(256) void gemm_out(const bf16* __restrict__ A,
                                                const bf16* __restrict__ Bw,
                                                float* __restrict__ Cout) {
  __shared__ bf16 As[128 * 32];
  __shared__ bf16 Bs[128 * 32];
  const int tid = threadIdx.x;
  const int w = tid >> 6, l = tid & 63;
  const int wr = w >> 1, wc = w & 1;
  const int lr = l & 15, lg = l >> 4;
  const int m0 = blockIdx.y * 128, n0 = blockIdx.x * 128;
  const int K = 1024, N = 1024;

  const int srow = l >> 2;
  const int skcol = (l & 3) << 3;

  const bf16* aP0 = A + (size_t)(m0 + w * 16 + srow) * K + skcol;
  const bf16* aP1 = A + (size_t)(m0 + 64 + w * 16 + srow) * K + skcol;
  const bf16* bP0 = Bw + (size_t)(n0 + w * 16 + srow) * K + skcol;
  const bf16* bP1 = Bw + (size_t)(n0 + 64 + w * 16 + srow) * K + skcol;
  bf16* aL0 = As + (w * 64 + l) * 8;
  bf16* aL1 = As + ((4 + w) * 64 + l) * 8;
  bf16* bL0 = Bs + (w * 64 + l) * 8;
  bf16* bL1 = Bs + ((4 + w) * 64 + l) * 8;

  f32x4 acc[4][4] = {};

  for (int kt = 0; kt < K; kt += 32) {
    gload16(aP0 + kt, aL0);
    gload16(aP1 + kt, aL1);
    gload16(bP0 + kt, bL0);
    gload16(bP1 + kt, bL1);
    __syncthreads();
    bf16x8 af[4], bfg[4];
#pragma unroll
    for (int mi = 0; mi < 4; mi++)
      af[mi] = *(const bf16x8*)&As[(wr * 64 + mi * 16 + lr) * 32 + lg * 8];
#pragma unroll
    for (int ni = 0; ni < 4; ni++)
      bfg[ni] = *(const bf16x8*)&Bs[(wc * 64 + ni * 16 + lr) * 32 + lg * 8];
#pragma unroll
    for (int mi = 0; mi < 4; mi++)
#pragma unroll
      for (int ni = 0; ni < 4; ni++)
        acc[mi][ni] = __builtin_amdgcn_mfma_f32_16x16x32_bf16(af[mi], bfg[ni], acc[mi][ni], 0, 0, 0);
    __syncthreads();
  }

#pragma unroll
  for (int mi = 0; mi < 4; mi++)
#pragma unroll
    for (int ni = 0; ni < 4; ni++)
#pragma unroll
      for (int r = 0; r < 4; r++) {
        const int m = m0 + wr * 64 + mi * 16 + lg * 4 + r;
        const int n = n0 + wc * 64 + ni * 16 + lr;
        Cout[(size_t)m * N + n] = acc[mi][ni][r];
      }
}

// ---------------- RoPE in-place on [B,H,S,D] bf16 (q then k) ----------------
__global__ __launch_bounds__(256) void rope_kernel(bf16* __restrict__ q, bf16* __restrict__ k) {
  int idx = blockIdx.x * 256 + threadIdx.x;
  bf16* base = (idx < (1 << 19)) ? q : k;
  int gg = idx & ((1 << 19) - 1);
  int s = (gg >> 3) & 2047;
  int d0 = (gg & 7) << 3;
  bf16* p = base + (size_t)gg * 8;
  bf16x8 v = *(bf16x8*)p;
  bf16x8 o;
  const float nl = -9.210340371976184f / 32.0f;    // -ln(10000)/32
#pragma unroll
  for (int pr = 0; pr < 4; pr++) {
    int d = d0 + 2 * pr;
    float x0 = (float)v[2 * pr], x1 = (float)v[2 * pr + 1];
    float th0 = s * expf((float)(d & 31) * nl);
    float th1 = s * expf((float)((d + 1) & 31) * nl);
    float c0 = cosf(th0), s0 = sinf(th0);
    float c1 = cosf(th1), s1 = sinf(th1);
    o[2 * pr]     = (bf16)(x0 * c0 - x1 * s0);
    o[2 * pr + 1] = (bf16)(x1 * c1 + x0 * s1);
  }
  *(bf16x8*)p = o;
}

// ---------------- flash attention, causal ----------------
// KVBLK=64. V loads hoisted above QK^T (independent of softmax) so V latency
// hides under QK+softmax; only one exposed load-latency per tile.
// Swapped QK^T (S^T: col=q=lane&15) keeps softmax state per-lane.
// PV k-permutation pi(8g+4s+r)=16s+4g+r makes the P fragment exactly the
// registers each lane holds; V fragments loaded with the matching layout.
__global__ __launch_bounds__(256) void attn_kernel(const bf16* __restrict__ qb,
                                                   const bf16* __restrict__ kb,
                                                   const bf16* __restrict__ vtb,
                                                   bf16* __restrict__ ob) {
  const int tid = threadIdx.x;
  const int w = tid >> 6, l = tid & 63;
  const int lr = l & 15, lg = l >> 4;
  const int bid = blockIdx.x;
  const int bh = bid & 31;                  // assuming round-robin XCD: 4 bh/XCD -> K,V L2-resident
  const int qt = 31 - (bid >> 5);           // heavy q-tiles dispatched first
  const int q0 = qt * 64 + w * 16;
  const bf16* qh = qb + (size_t)bh * (kS * kD);
  const bf16* kh = kb + (size_t)bh * (kS * kD);
  const bf16* vh = vtb + (size_t)bh * (kS * kD);
  const int b = bh >> 4, h = bh & 15;

  bf16x8 qf[2];
#pragma unroll
  for (int c = 0; c < 2; c++)
    qf[c] = *(const bf16x8*)&qh[(size_t)(q0 + lr) * kD + c * 32 + lg * 8];

  float m_run = -1e30f, l_run = 0.0f;
  f32x4 o[4] = {};
  const int q = q0 + lr;
  const int ntiles = q0 / 64 + 1;

  for (int t = 0; t < ntiles; t++) {
    const int kv0 = t * 64;
    // --- issue K loads, then V loads (all independent of softmax state) ---
    bf16x8 kf[4][2];
#pragma unroll
    for (int s = 0; s < 4; s++)
#pragma unroll
      for (int c = 0; c < 2; c++)
        kf[s][c] = *(const bf16x8*)&kh[(size_t)(kv0 + s * 16 + lr) * kD + c * 32 + lg * 8];
    bf16x4 vl[4][2][2];
#pragma unroll
    for (int c = 0; c < 4; c++)
#pragma unroll
      for (int f = 0; f < 2; f++) {
        const bf16* vrow = &vh[(size_t)(c * 16 + lr) * kS + kv0 + f * 32 + lg * 4];
        vl[c][f][0] = *(const bf16x4*)vrow;
        vl[c][f][1] = *(const bf16x4*)(vrow + 16);
      }
    // --- QK^T ---
    f32x4 sa[4] = {};
    __builtin_amdgcn_s_setprio(1);
#pragma unroll
    for (int s = 0; s < 4; s++) {
      sa[s] = __builtin_amdgcn_mfma_f32_16x16x32_bf16(kf[s][0], qf[0], sa[s], 0, 0, 0);
      sa[s] = __builtin_amdgcn_mfma_f32_16x16x32_bf16(kf[s][1], qf[1], sa[s], 0, 0, 0);
    }
    __builtin_amdgcn_s_setprio(0);
    // --- softmax (mask only the diagonal tile) ---
    float p[4][4];
    float tm = -1e30f;
    const bool maskt = (t == ntiles - 1);
#pragma unroll
    for (int s = 0; s < 4; s++)
#pragma unroll
      for (int r = 0; r < 4; r++) {
        float v = sa[s][r] * 0.125f;
        if (maskt) {
          int kk = kv0 + s * 16 + lg * 4 + r;
          v = (kk <= q) ? v : -1e30f;
        }
        p[s][r] = v;
        tm = fmaxf(tm, v);
      }
    tm = fmaxf(tm, __shfl_xor(tm, 16));
    tm = fmaxf(tm, __shfl_xor(tm, 32));
    const float m_new = fmaxf(m_run, tm);
    const float f = __expf(m_run - m_new);
    float ts = 0.0f;
#pragma unroll
    for (int s = 0; s < 4; s++)
#pragma unroll
      for (int r = 0; r < 4; r++) {
        float e = __expf(p[s][r] - m_new);
        p[s][r] = e;
        ts += e;
      }
    ts += __shfl_xor(ts, 16);
    ts += __shfl_xor(ts, 32);
    l_run = l_run * f + ts;
    m_run = m_new;
#pragma unroll
    for (int c = 0; c < 4; c++) o[c] *= f;

    bf16x8 pf[2];
#pragma unroll
    for (int f2 = 0; f2 < 2; f2++)
#pragma unroll
      for (int j = 0; j < 8; j++)
        pf[f2][j] = (bf16)p[2 * f2 + (j >> 2)][j & 3];

    // --- PV ---
    __builtin_amdgcn_s_setprio(1);
#pragma unroll
    for (int c = 0; c < 4; c++)
#pragma unroll
      for (int f2 = 0; f2 < 2; f2++) {
        bf16x8 af;
        af[0] = vl[c][f2][0][0]; af[1] = vl[c][f2][0][1];
        af[2] = vl[c][f2][0][2]; af[3] = vl[c][f2][0][3];
        af[4] = vl[c][f2][1][0]; af[5] = vl[c][f2][1][1];
        af[6] = vl[c][f2][1][2]; af[7] = vl[c][f2][1][3];
        o[c] = __builtin_amdgcn_mfma_f32_16x16x32_bf16(af, pf[f2], o[c], 0, 0, 0);
      }
    __builtin_amdgcn_s_setprio(0);
  }

  const float inv = 1.0f / l_run;
#pragma unroll
  for (int c = 0; c < 4; c++) {
    bf16x4 ov;
#pragma unroll
    for (int r = 0; r < 4; r++) ov[r] = (bf16)(o[c][r] * inv);
    size_t addr = ((size_t)(b * kS + q0 + lr)) * (kH * kD) + h * 64 + c * 16 + lg * 4;
    *(bf16x4*)&ob[addr] = ov;
  }
}

extern "C" void kernel_launch(void* const* d_in, const int* in_sizes, int n_in,
                              void* d_out, int out_size, void* d_ws, size_t ws_size,
                              hipStream_t stream) {
  const float* x  = (const float*)d_in[0];
  const float* wq = (const float*)d_in[1];
  const float* wk = (const float*)d_in[2];
  const float* wv = (const float*)d_in[3];
  const float* wo = (const float*)d_in[4];

  bf16* xb  = (bf16*)d_ws;            // 4M elems each (8 MiB)
  bf16* qb  = xb + (1 << 22);
  bf16* kb  = qb + (1 << 22);
  bf16* vtb = kb + (1 << 22);
  bf16* ab  = vtb + (1 << 22);
  bf16* wqb = ab + (1 << 22);         // 1M elems each (2 MiB)
  bf16* wkb = wqb + (1 << 20);
  bf16* wvb = wkb + (1 << 20);
  bf16* wob = wvb + (1 << 20);

  cast_all_kernel<<<8192, 256, 0, stream>>>(x, wq, wk, wv, wo, xb, wqb, wkb, wvb, wob);
  gemm_qkv<<<768, 256, 0, stream>>>(xb, wqb, wkb, wvb, qb, kb, vtb);
  rope_kernel<<<4096, 256, 0, stream>>>(qb, kb);
  attn_kernel<<<1024, 256, 0, stream>>>(qb, kb, vtb, ab);
  gemm_out<<<dim3(8, 32), 256, 0, stream>>>(ab, wob, (float*)d_out);
}

// Round 4
// 214.577 us; speedup vs baseline: 2.1856x; 1.4685x over previous
//
#include <hip/hip_runtime.h>
#include <cstdint>
#include <cstddef>

typedef __bf16 bf16;
typedef __attribute__((ext_vector_type(8))) __bf16 bf16x8;
typedef __attribute__((ext_vector_type(4))) __bf16 bf16x4;
typedef __attribute__((ext_vector_type(4))) float f32x4;

constexpr int kS = 2048;
constexpr int kH = 16;
constexpr int kD = 64;

__device__ __forceinline__ void gload16(const bf16* g, bf16* l) {
  __builtin_amdgcn_global_load_lds((const __attribute__((address_space(1))) void*)g,
                                   (__attribute__((address_space(3))) void*)l, 16, 0, 0);
}

// ---------------- cast fp32 -> bf16 (x + 4 weights) ----------------
__global__ __launch_bounds__(256) void cast_all_kernel(
    const float* __restrict__ x, const float* __restrict__ wq, const float* __restrict__ wk,
    const float* __restrict__ wv, const float* __restrict__ wo,
    bf16* __restrict__ xb, bf16* __restrict__ wqb, bf16* __restrict__ wkb,
    bf16* __restrict__ wvb, bf16* __restrict__ wob) {
  int idx = blockIdx.x * 256 + threadIdx.x;   // 2M threads, 4 floats each
  const float* src; bf16* dst; int i;
  if (idx < (1 << 20)) { src = x; dst = xb; i = idx << 2; }
  else {
    int r = idx - (1 << 20);
    int t = r >> 18;
    i = (r & ((1 << 18) - 1)) << 2;
    src = (t == 0) ? wq : (t == 1) ? wk : (t == 2) ? wv : wo;
    dst = (t == 0) ? wqb : (t == 1) ? wkb : (t == 2) ? wvb : wob;
  }
  float4 v = *(const float4*)(src + i);
  bf16x4 o;
  o[0] = (bf16)v.x; o[1] = (bf16)v.y; o[2] = (bf16)v.z; o[3] = (bf16)v.w;
  *(bf16x4*)(dst + i) = o;
}

// ---------------- fused QKV GEMM + RoPE + layout transforms ----------------
// C[m][n] = sum_k x[m][k] * W[n][k], W in {Wq,Wk,Wv} by n-region.
// q,k: RoPE applied in epilogue (fp32), stored [B,H,S,D] bf16.
// v: stored [B,H,D,S] bf16 with MFMA-ready 32-chunk permutation
//    (element kv=16*s2+4*g+r within chunk stored at pos 8*g+4*s2+r).
__global__ __launch_bounds__(256) void gemm_qkv(const bf16* __restrict__ A,
                                                const bf16* __restrict__ wq,
                                                const bf16* __restrict__ wk,
                                                const bf16* __restrict__ wv,
                                                bf16* __restrict__ qo,
                                                bf16* __restrict__ ko,
                                                bf16* __restrict__ vto) {
  __shared__ bf16 As[128 * 32];
  __shared__ bf16 Bs[128 * 32];
  const int tid = threadIdx.x;
  const int w = tid >> 6, l = tid & 63;
  const int wr = w >> 1, wc = w & 1;
  const int lr = l & 15, lg = l >> 4;

  // XCD-aware remap of 768 blocks (768 % 8 == 0 -> bijective)
  const int fid = (blockIdx.x & 7) * 96 + (blockIdx.x >> 3);
  const int mblk = fid & 31;            // 0..31
  const int ntile = fid >> 5;           // 0..23
  const int which = ntile >> 3;         // 0=q 1=k 2=v
  const int m0 = mblk * 128;
  const int n0 = (ntile & 7) * 128;
  const bf16* Bw = (which == 0) ? wq : (which == 1) ? wk : wv;

  const int srow = l >> 2;
  const int skcol = (l & 3) << 3;
  const int K = 1024;

  const bf16* aP0 = A + (size_t)(m0 + w * 16 + srow) * K + skcol;
  const bf16* aP1 = A + (size_t)(m0 + 64 + w * 16 + srow) * K + skcol;
  const bf16* bP0 = Bw + (size_t)(n0 + w * 16 + srow) * K + skcol;
  const bf16* bP1 = Bw + (size_t)(n0 + 64 + w * 16 + srow) * K + skcol;
  bf16* aL0 = As + (w * 64 + l) * 8;
  bf16* aL1 = As + ((4 + w) * 64 + l) * 8;
  bf16* bL0 = Bs + (w * 64 + l) * 8;
  bf16* bL1 = Bs + ((4 + w) * 64 + l) * 8;

  f32x4 acc[4][4] = {};

  for (int kt = 0; kt < K; kt += 32) {
    gload16(aP0 + kt, aL0);
    gload16(aP1 + kt, aL1);
    gload16(bP0 + kt, bL0);
    gload16(bP1 + kt, bL1);
    __syncthreads();
    bf16x8 af[4], bfg[4];
#pragma unroll
    for (int mi = 0; mi < 4; mi++)
      af[mi] = *(const bf16x8*)&As[(wr * 64 + mi * 16 + lr) * 32 + lg * 8];
#pragma unroll
    for (int ni = 0; ni < 4; ni++)
      bfg[ni] = *(const bf16x8*)&Bs[(wc * 64 + ni * 16 + lr) * 32 + lg * 8];
#pragma unroll
    for (int mi = 0; mi < 4; mi++)
#pragma unroll
      for (int ni = 0; ni < 4; ni++)
        acc[mi][ni] = __builtin_amdgcn_mfma_f32_16x16x32_bf16(af[mi], bfg[ni], acc[mi][ni], 0, 0, 0);
    __syncthreads();
  }

  // hoisted inv-freq per ni: d&31 = (wc*64 + ni*16 + lr) & 31 (independent of mi,r)
  float invf_[4];
#pragma unroll
  for (int ni = 0; ni < 4; ni++) {
    int d31 = ((n0 + wc * 64 + ni * 16 + lr) & 63) & 31;
    invf_[ni] = exp2f((float)d31 * -0.41524100480466348f);   // 10000^(-(d&31)/32)
  }

#pragma unroll
  for (int mi = 0; mi < 4; mi++) {
#pragma unroll
    for (int ni = 0; ni < 4; ni++) {
#pragma unroll
      for (int r = 0; r < 4; r++) {
        const int m = m0 + wr * 64 + mi * 16 + lg * 4 + r;   // token index
        const int n = n0 + wc * 64 + ni * 16 + lr;           // emb index (h*64+d)
        float v = acc[mi][ni][r];
        const int st = m & 2047;                              // seq position
        const size_t bh = (size_t)(m >> 11) * kH + (n >> 6);
        if (which < 2) {
          // RoPE: partner element is the lane with lr^1 (n^1)
          float vp = __shfl_xor(v, 1);
          const int d = n & 63;
          float th = (float)st * invf_[ni];
          float sth = __sinf(th), cth = __cosf(th);
          float rv = v * cth + ((d & 1) ? vp : -vp) * sth;
          bf16* dst = which ? ko : qo;                       // [B,H,S,D]
          dst[((bh << 11) + st) * kD + (n & 63)] = (bf16)rv;
        } else {                                             // [B,H,D,S] permuted
          int pos = (st & ~31) | (((st >> 2) & 3) << 3) | (((st >> 4) & 1) << 2) | (st & 3);
          vto[((bh * kD + (n & 63)) << 11) + pos] = (bf16)v;
        }
      }
    }
  }
}

// ---------------- final GEMM C = A @ Wo^T, fp32 out ----------------
__global__ __launch_bounds__(256) void gemm_out(const bf16* __restrict__ A,
                                                const bf16* __restrict__ Bw,
                                                float* __restrict__ Cout) {
  __shared__ bf16 As[128 * 32];
  __shared__ bf16 Bs[128 * 32];
  const int tid = threadIdx.x;
  const int w = tid >> 6, l = tid & 63;
  const int wr = w >> 1, wc = w & 1;
  const int lr = l & 15, lg = l >> 4;
  const int m0 = blockIdx.y * 128, n0 = blockIdx.x * 128;
  const int K = 1024, N = 1024;

  const int srow = l >> 2;
  const int skcol = (l & 3) << 3;

  const bf16* aP0 = A + (size_t)(m0 + w * 16 + srow) * K + skcol;
  const bf16* aP1 = A + (size_t)(m0 + 64 + w * 16 + srow) * K + skcol;
  const bf16* bP0 = Bw + (size_t)(n0 + w * 16 + srow) * K + skcol;
  const bf16* bP1 = Bw + (size_t)(n0 + 64 + w * 16 + srow) * K + skcol;
  bf16* aL0 = As + (w * 64 + l) * 8;
  bf16* aL1 = As + ((4 + w) * 64 + l) * 8;
  bf16* bL0 = Bs + (w * 64 + l) * 8;
  bf16* bL1 = Bs + ((4 + w) * 64 + l) * 8;

  f32x4 acc[4][4] = {};

  for (int kt = 0; kt < K; kt += 32) {
    gload16(aP0 + kt, aL0);
    gload16(aP1 + kt, aL1);
    gload16(bP0 + kt, bL0);
    gload16(bP1 + kt, bL1);
    __syncthreads();
    bf16x8 af[4], bfg[4];
#pragma unroll
    for (int mi = 0; mi < 4; mi++)
      af[mi] = *(const bf16x8*)&As[(wr * 64 + mi * 16 + lr) * 32 + lg * 8];
#pragma unroll
    for (int ni = 0; ni < 4; ni++)
      bfg[ni] = *(const bf16x8*)&Bs[(wc * 64 + ni * 16 + lr) * 32 + lg * 8];
#pragma unroll
    for (int mi = 0; mi < 4; mi++)
#pragma unroll
      for (int ni = 0; ni < 4; ni++)
        acc[mi][ni] = __builtin_amdgcn_mfma_f32_16x16x32_bf16(af[mi], bfg[ni], acc[mi][ni], 0, 0, 0);
    __syncthreads();
  }

#pragma unroll
  for (int mi = 0; mi < 4; mi++)
#pragma unroll
    for (int ni = 0; ni < 4; ni++)
#pragma unroll
      for (int r = 0; r < 4; r++) {
        const int m = m0 + wr * 64 + mi * 16 + lg * 4 + r;
        const int n = n0 + wc * 64 + ni * 16 + lr;
        Cout[(size_t)m * N + n] = acc[mi][ni][r];
      }
}

// ---------------- flash attention, causal, defer-max, double-buffered ----------------
// q,k: [B,H,S,D] bf16 (rope'd). v: [B,H,D,S] bf16 MFMA-ready-permuted. out: [B,S,E] bf16.
// Swapped QK^T (S^T: col=q=lane&15) keeps softmax state per-lane.
// Defer-max: m_run starts at 8; exp never waits on a wave reduction. Guard
// rescale only if any tile score exceeds m_run+20 (overflow-safe, never for
// typical data). l is a per-lane partial, reduced once at the end.
// K and V register-double-buffered: loads for tile t+1 issued before compute(t).

#define LOADKV(KF, VF, KV0)                                                              \
  {                                                                                      \
    _Pragma("unroll") for (int s_ = 0; s_ < 4; s_++)                                     \
      _Pragma("unroll") for (int c_ = 0; c_ < 2; c_++)                                   \
        KF[s_][c_] = *(const bf16x8*)&kh[(size_t)((KV0) + s_ * 16 + lr) * kD + c_ * 32 + lg * 8]; \
    _Pragma("unroll") for (int c_ = 0; c_ < 4; c_++)                                     \
      _Pragma("unroll") for (int f_ = 0; f_ < 2; f_++)                                   \
        VF[c_][f_] = *(const bf16x8*)&vh[(size_t)(c_ * 16 + lr) * kS + (KV0) + f_ * 32 + lg * 8]; \
  }

#define COMPUTE(KF, VF, T)                                                               \
  {                                                                                      \
    f32x4 sa_[4] = {};                                                                   \
    __builtin_amdgcn_s_setprio(1);                                                       \
    _Pragma("unroll") for (int s_ = 0; s_ < 4; s_++) {                                   \
      sa_[s_] = __builtin_amdgcn_mfma_f32_16x16x32_bf16(KF[s_][0], qf[0], sa_[s_], 0, 0, 0); \
      sa_[s_] = __builtin_amdgcn_mfma_f32_16x16x32_bf16(KF[s_][1], qf[1], sa_[s_], 0, 0, 0); \
    }                                                                                    \
    __builtin_amdgcn_s_setprio(0);                                                       \
    const bool maskt_ = ((T) == ntiles - 1);                                             \
    float sc_[4][4];                                                                     \
    float tml_ = -1e30f;                                                                 \
    _Pragma("unroll") for (int s_ = 0; s_ < 4; s_++)                                     \
      _Pragma("unroll") for (int r_ = 0; r_ < 4; r_++) {                                 \
        float v_ = sa_[s_][r_] * 0.125f;                                                 \
        if (maskt_) {                                                                    \
          int kk_ = (T) * 64 + s_ * 16 + lg * 4 + r_;                                    \
          v_ = (kk_ <= q) ? v_ : -1e30f;                                                 \
        }                                                                                \
        sc_[s_][r_] = v_;                                                                \
        tml_ = fmaxf(tml_, v_);                                                          \
      }                                                                                  \
    if (__any(tml_ > m_run + 20.0f)) {                                                   \
      float tm_ = tml_;                                                                  \
      tm_ = fmaxf(tm_, __shfl_xor(tm_, 16));                                             \
      tm_ = fmaxf(tm_, __shfl_xor(tm_, 32));                                             \
      tm_ = fmaxf(tm_, m_run);                                                           \
      float f_ = __expf(m_run - tm_);                                                    \
      _Pragma("unroll") for (int c_ = 0; c_ < 4; c_++) o[c_] *= f_;                      \
      lpart *= f_;                                                                       \
      m_run = tm_;                                                                       \
    }                                                                                    \
    bf16x8 pf_[2];                                                                       \
    float tsum_ = 0.0f;                                                                  \
    _Pragma("unroll") for (int s_ = 0; s_ < 4; s_++)                                     \
      _Pragma("unroll") for (int r_ = 0; r_ < 4; r_++) {                                 \
        float e_ = __expf(sc_[s_][r_] - m_run);                                          \
        tsum_ += e_;                                                                     \
        pf_[s_ >> 1][(s_ & 1) * 4 + r_] = (bf16)e_;                                      \
      }                                                                                  \
    lpart += tsum_;                                                                      \
    __builtin_amdgcn_s_setprio(1);                                                       \
    _Pragma("unroll") for (int c_ = 0; c_ < 4; c_++) {                                   \
      o[c_] = __builtin_amdgcn_mfma_f32_16x16x32_bf16(VF[c_][0], pf_[0], o[c_], 0, 0, 0); \
      o[c_] = __builtin_amdgcn_mfma_f32_16x16x32_bf16(VF[c_][1], pf_[1], o[c_], 0, 0, 0); \
    }                                                                                    \
    __builtin_amdgcn_s_setprio(0);                                                       \
  }

__global__ __launch_bounds__(256, 2) void attn_kernel(const bf16* __restrict__ qb,
                                                      const bf16* __restrict__ kb,
                                                      const bf16* __restrict__ vtb,
                                                      bf16* __restrict__ ob) {
  const int tid = threadIdx.x;
  const int w = tid >> 6, l = tid & 63;
  const int lr = l & 15, lg = l >> 4;
  const int bid = blockIdx.x;
  const int bh = bid & 31;                  // round-robin XCD: 4 bh/XCD -> K,V L2-resident
  const int qt = 31 - (bid >> 5);           // heavy q-tiles dispatched first
  const int q0 = qt * 64 + w * 16;
  const bf16* qh = qb + (size_t)bh * (kS * kD);
  const bf16* kh = kb + (size_t)bh * (kS * kD);
  const bf16* vh = vtb + (size_t)bh * (kS * kD);
  const int b = bh >> 4, h = bh & 15;

  bf16x8 qf[2];
#pragma unroll
  for (int c = 0; c < 2; c++)
    qf[c] = *(const bf16x8*)&qh[(size_t)(q0 + lr) * kD + c * 32 + lg * 8];

  float m_run = 8.0f, lpart = 0.0f;
  f32x4 o[4] = {};
  const int q = q0 + lr;
  const int ntiles = q0 / 64 + 1;

  bf16x8 kA[4][2], vA[4][2], kB[4][2], vB[4][2];
  LOADKV(kA, vA, 0)
  int t = 0;
  for (;;) {
    if (t + 1 < ntiles) LOADKV(kB, vB, (t + 1) * 64)
    COMPUTE(kA, vA, t)
    ++t;
    if (t == ntiles) break;
    if (t + 1 < ntiles) LOADKV(kA, vA, (t + 1) * 64)
    COMPUTE(kB, vB, t)
    ++t;
    if (t == ntiles) break;
  }

  float l_tot = lpart;
  l_tot += __shfl_xor(l_tot, 16);
  l_tot += __shfl_xor(l_tot, 32);
  const float inv = 1.0f / l_tot;
#pragma unroll
  for (int c = 0; c < 4; c++) {
    bf16x4 ov;
#pragma unroll
    for (int r = 0; r < 4; r++) ov[r] = (bf16)(o[c][r] * inv);
    size_t addr = ((size_t)(b * kS + q0 + lr)) * (kH * kD) + h * 64 + c * 16 + lg * 4;
    *(bf16x4*)&ob[addr] = ov;
  }
}

extern "C" void kernel_launch(void* const* d_in, const int* in_sizes, int n_in,
                              void* d_out, int out_size, void* d_ws, size_t ws_size,
                              hipStream_t stream) {
  const float* x  = (const float*)d_in[0];
  const float* wq = (const float*)d_in[1];
  const float* wk = (const float*)d_in[2];
  const float* wv = (const float*)d_in[3];
  const float* wo = (const float*)d_in[4];

  bf16* xb  = (bf16*)d_ws;            // 4M elems each (8 MiB)
  bf16* qb  = xb + (1 << 22);
  bf16* kb  = qb + (1 << 22);
  bf16* vtb = kb + (1 << 22);
  bf16* ab  = vtb + (1 << 22);
  bf16* wqb = ab + (1 << 22);         // 1M elems each (2 MiB)
  bf16* wkb = wqb + (1 << 20);
  bf16* wvb = wkb + (1 << 20);
  bf16* wob = wvb + (1 << 20);

  cast_all_kernel<<<8192, 256, 0, stream>>>(x, wq, wk, wv, wo, xb, wqb, wkb, wvb, wob);
  gemm_qkv<<<768, 256, 0, stream>>>(xb, wqb, wkb, wvb, qb, kb, vtb);
  attn_kernel<<<1024, 256, 0, stream>>>(qb, kb, vtb, ab);
  gemm_out<<<dim3(8, 32), 256, 0, stream>>>(ab, wob, (float*)d_out);
}

// Round 5
// 132.823 us; speedup vs baseline: 3.5309x; 1.6155x over previous
//
#include <hip/hip_runtime.h>
#include <cstdint>
#include <cstddef>

typedef __bf16 bf16;
typedef __attribute__((ext_vector_type(8))) __bf16 bf16x8;
typedef __attribute__((ext_vector_type(4))) __bf16 bf16x4;
typedef __attribute__((ext_vector_type(4))) float f32x4;

constexpr int kS = 2048;
constexpr int kH = 16;
constexpr int kD = 64;

__device__ __forceinline__ void gload16(const bf16* g, bf16* l) {
  __builtin_amdgcn_global_load_lds((const __attribute__((address_space(1))) void*)g,
                                   (__attribute__((address_space(3))) void*)l, 16, 0, 0);
}

// ---------------- cast fp32 -> bf16 (x + 4 weights) ----------------
__global__ __launch_bounds__(256) void cast_all_kernel(
    const float* __restrict__ x, const float* __restrict__ wq, const float* __restrict__ wk,
    const float* __restrict__ wv, const float* __restrict__ wo,
    bf16* __restrict__ xb, bf16* __restrict__ wqb, bf16* __restrict__ wkb,
    bf16* __restrict__ wvb, bf16* __restrict__ wob) {
  int idx = blockIdx.x * 256 + threadIdx.x;   // 2M threads, 4 floats each
  const float* src; bf16* dst; int i;
  if (idx < (1 << 20)) { src = x; dst = xb; i = idx << 2; }
  else {
    int r = idx - (1 << 20);
    int t = r >> 18;
    i = (r & ((1 << 18) - 1)) << 2;
    src = (t == 0) ? wq : (t == 1) ? wk : (t == 2) ? wv : wo;
    dst = (t == 0) ? wqb : (t == 1) ? wkb : (t == 2) ? wvb : wob;
  }
  float4 v = *(const float4*)(src + i);
  bf16x4 o;
  o[0] = (bf16)v.x; o[1] = (bf16)v.y; o[2] = (bf16)v.z; o[3] = (bf16)v.w;
  *(bf16x4*)(dst + i) = o;
}

// ---------------- fused QKV GEMM + RoPE + layout transforms ----------------
__global__ __launch_bounds__(256) void gemm_qkv(const bf16* __restrict__ A,
                                                const bf16* __restrict__ wq,
                                                const bf16* __restrict__ wk,
                                                const bf16* __restrict__ wv,
                                                bf16* __restrict__ qo,
                                                bf16* __restrict__ ko,
                                                bf16* __restrict__ vto) {
  __shared__ bf16 As[128 * 32];
  __shared__ bf16 Bs[128 * 32];
  const int tid = threadIdx.x;
  const int w = tid >> 6, l = tid & 63;
  const int wr = w >> 1, wc = w & 1;
  const int lr = l & 15, lg = l >> 4;

  // XCD-aware remap of 768 blocks (768 % 8 == 0 -> bijective)
  const int fid = (blockIdx.x & 7) * 96 + (blockIdx.x >> 3);
  const int mblk = fid & 31;            // 0..31
  const int ntile = fid >> 5;           // 0..23
  const int which = ntile >> 3;         // 0=q 1=k 2=v
  const int m0 = mblk * 128;
  const int n0 = (ntile & 7) * 128;
  const bf16* Bw = (which == 0) ? wq : (which == 1) ? wk : wv;

  const int srow = l >> 2;
  const int skcol = (l & 3) << 3;
  const int K = 1024;

  const bf16* aP0 = A + (size_t)(m0 + w * 16 + srow) * K + skcol;
  const bf16* aP1 = A + (size_t)(m0 + 64 + w * 16 + srow) * K + skcol;
  const bf16* bP0 = Bw + (size_t)(n0 + w * 16 + srow) * K + skcol;
  const bf16* bP1 = Bw + (size_t)(n0 + 64 + w * 16 + srow) * K + skcol;
  bf16* aL0 = As + (w * 64 + l) * 8;
  bf16* aL1 = As + ((4 + w) * 64 + l) * 8;
  bf16* bL0 = Bs + (w * 64 + l) * 8;
  bf16* bL1 = Bs + ((4 + w) * 64 + l) * 8;

  f32x4 acc[4][4] = {};

  for (int kt = 0; kt < K; kt += 32) {
    gload16(aP0 + kt, aL0);
    gload16(aP1 + kt, aL1);
    gload16(bP0 + kt, bL0);
    gload16(bP1 + kt, bL1);
    __syncthreads();
    bf16x8 af[4], bfg[4];
#pragma unroll
    for (int mi = 0; mi < 4; mi++)
      af[mi] = *(const bf16x8*)&As[(wr * 64 + mi * 16 + lr) * 32 + lg * 8];
#pragma unroll
    for (int ni = 0; ni < 4; ni++)
      bfg[ni] = *(const bf16x8*)&Bs[(wc * 64 + ni * 16 + lr) * 32 + lg * 8];
#pragma unroll
    for (int mi = 0; mi < 4; mi++)
#pragma unroll
      for (int ni = 0; ni < 4; ni++)
        acc[mi][ni] = __builtin_amdgcn_mfma_f32_16x16x32_bf16(af[mi], bfg[ni], acc[mi][ni], 0, 0, 0);
    __syncthreads();
  }

  float invf_[4];
#pragma unroll
  for (int ni = 0; ni < 4; ni++) {
    int d31 = ((n0 + wc * 64 + ni * 16 + lr) & 63) & 31;
    invf_[ni] = exp2f((float)d31 * -0.41524100480466348f);   // 10000^(-(d&31)/32)
  }

#pragma unroll
  for (int mi = 0; mi < 4; mi++) {
#pragma unroll
    for (int ni = 0; ni < 4; ni++) {
#pragma unroll
      for (int r = 0; r < 4; r++) {
        const int m = m0 + wr * 64 + mi * 16 + lg * 4 + r;   // token index
        const int n = n0 + wc * 64 + ni * 16 + lr;           // emb index (h*64+d)
        float v = acc[mi][ni][r];
        const int st = m & 2047;                              // seq position
        const size_t bh = (size_t)(m >> 11) * kH + (n >> 6);
        if (which < 2) {
          float vp = __shfl_xor(v, 1);
          const int d = n & 63;
          float th = (float)st * invf_[ni];
          float sth = __sinf(th), cth = __cosf(th);
          float rv = v * cth + ((d & 1) ? vp : -vp) * sth;
          bf16* dst = which ? ko : qo;                       // [B,H,S,D]
          dst[((bh << 11) + st) * kD + (n & 63)] = (bf16)rv;
        } else {                                             // [B,H,D,S] permuted
          int pos = (st & ~31) | (((st >> 2) & 3) << 3) | (((st >> 4) & 1) << 2) | (st & 3);
          vto[((bh * kD + (n & 63)) << 11) + pos] = (bf16)v;
        }
      }
    }
  }
}

// ---------------- final GEMM C = A @ Wo^T, fp32 out ----------------
__global__ __launch_bounds__(256) void gemm_out(const bf16* __restrict__ A,
                                                const bf16* __restrict__ Bw,
                                                float* __restrict__ Cout) {
  __shared__ bf16 As[128 * 32];
  __shared__ bf16 Bs[128 * 32];
  const int tid = threadIdx.x;
  const int w = tid >> 6, l = tid & 63;
  const int wr = w >> 1, wc = w & 1;
  const int lr = l & 15, lg = l >> 4;
  const int m0 = blockIdx.y * 128, n0 = blockIdx.x * 128;
  const int K = 1024, N = 1024;

  const int srow = l >> 2;
  const int skcol = (l & 3) << 3;

  const bf16* aP0 = A + (size_t)(m0 + w * 16 + srow) * K + skcol;
  const bf16* aP1 = A + (size_t)(m0 + 64 + w * 16 + srow) * K + skcol;
  const bf16* bP0 = Bw + (size_t)(n0 + w * 16 + srow) * K + skcol;
  const bf16* bP1 = Bw + (size_t)(n0 + 64 + w * 16 + srow) * K + skcol;
  bf16* aL0 = As + (w * 64 + l) * 8;
  bf16* aL1 = As + ((4 + w) * 64 + l) * 8;
  bf16* bL0 = Bs + (w * 64 + l) * 8;
  bf16* bL1 = Bs + ((4 + w) * 64 + l) * 8;

  f32x4 acc[4][4] = {};

  for (int kt = 0; kt < K; kt += 32) {
    gload16(aP0 + kt, aL0);
    gload16(aP1 + kt, aL1);
    gload16(bP0 + kt, bL0);
    gload16(bP1 + kt, bL1);
    __syncthreads();
    bf16x8 af[4], bfg[4];
#pragma unroll
    for (int mi = 0; mi < 4; mi++)
      af[mi] = *(const bf16x8*)&As[(wr * 64 + mi * 16 + lr) * 32 + lg * 8];
#pragma unroll
    for (int ni = 0; ni < 4; ni++)
      bfg[ni] = *(const bf16x8*)&Bs[(wc * 64 + ni * 16 + lr) * 32 + lg * 8];
#pragma unroll
    for (int mi = 0; mi < 4; mi++)
#pragma unroll
      for (int ni = 0; ni < 4; ni++)
        acc[mi][ni] = __builtin_amdgcn_mfma_f32_16x16x32_bf16(af[mi], bfg[ni], acc[mi][ni], 0, 0, 0);
    __syncthreads();
  }

#pragma unroll
  for (int mi = 0; mi < 4; mi++)
#pragma unroll
    for (int ni = 0; ni < 4; ni++)
#pragma unroll
      for (int r = 0; r < 4; r++) {
        const int m = m0 + wr * 64 + mi * 16 + lg * 4 + r;
        const int n = n0 + wc * 64 + ni * 16 + lr;
        Cout[(size_t)m * N + n] = acc[mi][ni][r];
      }
}

// ---------------- flash attention, causal, LDS-staged, pair-balanced ----------------
// Block = (bh, pair p): processes q-tile (31-p) then q-tile p -> 33 kv-tile
// iterations per block, uniform. 512 blocks, 256 threads.
// Per kv-tile: K,V (8KB each) staged to LDS in exact fragment order via
// global_load_lds (4 issues/wave), double-buffered, one barrier per tile
// (T3-lite: STAGE(next); compute(cur); [vmcnt drain]; barrier).
// Swapped QK^T keeps softmax per-lane; defer-max skips wave reductions.
// V comes pre-permuted ([B,H,D,S] with 32-chunk MFMA permutation) so V
// fragments are single b128 reads.

#define STAGE(BUF, KV0)                                                                  \
  {                                                                                      \
    const bf16* kg_ = kh + (size_t)((KV0) + w * 16 + lr) * 64 + lg * 8;                  \
    gload16(kg_,      &Ks[BUF][(w * 2 + 0) * 512 + l * 8]);                              \
    gload16(kg_ + 32, &Ks[BUF][(w * 2 + 1) * 512 + l * 8]);                              \
    const bf16* vg_ = vh + (size_t)(w * 16 + lr) * 2048 + (KV0) + lg * 8;                \
    gload16(vg_,      &Vs[BUF][(w * 2 + 0) * 512 + l * 8]);                              \
    gload16(vg_ + 32, &Vs[BUF][(w * 2 + 1) * 512 + l * 8]);                              \
  }

#define COMPUTE(BUF, DIAG, O, MRUN, LPART, QF, QROW, KVB)                                \
  {                                                                                      \
    bf16x8 kf_[4][2], vf_[4][2];                                                         \
    _Pragma("unroll") for (int s_ = 0; s_ < 4; s_++)                                     \
      _Pragma("unroll") for (int c_ = 0; c_ < 2; c_++)                                   \
        kf_[s_][c_] = *(const bf16x8*)&Ks[BUF][(s_ * 2 + c_) * 512 + l * 8];             \
    _Pragma("unroll") for (int c_ = 0; c_ < 4; c_++)                                     \
      _Pragma("unroll") for (int f_ = 0; f_ < 2; f_++)                                   \
        vf_[c_][f_] = *(const bf16x8*)&Vs[BUF][(c_ * 2 + f_) * 512 + l * 8];             \
    f32x4 sa_[4] = {};                                                                   \
    __builtin_amdgcn_s_setprio(1);                                                       \
    _Pragma("unroll") for (int s_ = 0; s_ < 4; s_++) {                                   \
      sa_[s_] = __builtin_amdgcn_mfma_f32_16x16x32_bf16(kf_[s_][0], QF[0], sa_[s_], 0, 0, 0); \
      sa_[s_] = __builtin_amdgcn_mfma_f32_16x16x32_bf16(kf_[s_][1], QF[1], sa_[s_], 0, 0, 0); \
    }                                                                                    \
    __builtin_amdgcn_s_setprio(0);                                                       \
    float sc_[4][4];                                                                     \
    float tml_ = -1e30f;                                                                 \
    _Pragma("unroll") for (int s_ = 0; s_ < 4; s_++)                                     \
      _Pragma("unroll") for (int r_ = 0; r_ < 4; r_++) {                                 \
        float v_ = sa_[s_][r_] * 0.125f;                                                 \
        if (DIAG) {                                                                      \
          int kk_ = (KVB) + s_ * 16 + lg * 4 + r_;                                       \
          v_ = (kk_ <= (QROW)) ? v_ : -1e30f;                                            \
        }                                                                                \
        sc_[s_][r_] = v_;                                                                \
        tml_ = fmaxf(tml_, v_);                                                          \
      }                                                                                  \
    if (__any(tml_ > MRUN + 20.0f)) {                                                    \
      float tm_ = tml_;                                                                  \
      tm_ = fmaxf(tm_, __shfl_xor(tm_, 16));                                             \
      tm_ = fmaxf(tm_, __shfl_xor(tm_, 32));                                             \
      tm_ = fmaxf(tm_, MRUN);                                                            \
      float f_ = __expf(MRUN - tm_);                                                     \
      _Pragma("unroll") for (int c_ = 0; c_ < 4; c_++) O[c_] *= f_;                      \
      LPART *= f_;                                                                       \
      MRUN = tm_;                                                                        \
    }                                                                                    \
    bf16x8 pf_[2];                                                                       \
    float ts_ = 0.0f;                                                                    \
    _Pragma("unroll") for (int s_ = 0; s_ < 4; s_++)                                     \
      _Pragma("unroll") for (int r_ = 0; r_ < 4; r_++) {                                 \
        float e_ = __expf(sc_[s_][r_] - MRUN);                                           \
        ts_ += e_;                                                                       \
        pf_[s_ >> 1][(s_ & 1) * 4 + r_] = (bf16)e_;                                      \
      }                                                                                  \
    LPART += ts_;                                                                        \
    __builtin_amdgcn_s_setprio(1);                                                       \
    _Pragma("unroll") for (int c_ = 0; c_ < 4; c_++) {                                   \
      O[c_] = __builtin_amdgcn_mfma_f32_16x16x32_bf16(vf_[c_][0], pf_[0], O[c_], 0, 0, 0); \
      O[c_] = __builtin_amdgcn_mfma_f32_16x16x32_bf16(vf_[c_][1], pf_[1], O[c_], 0, 0, 0); \
    }                                                                                    \
    __builtin_amdgcn_s_setprio(0);                                                       \
  }

#define EPILOG(O, LPART, Q0)                                                             \
  {                                                                                      \
    float lt_ = LPART;                                                                   \
    lt_ += __shfl_xor(lt_, 16);                                                          \
    lt_ += __shfl_xor(lt_, 32);                                                          \
    const float inv_ = 1.0f / lt_;                                                       \
    _Pragma("unroll") for (int c_ = 0; c_ < 4; c_++) {                                   \
      bf16x4 ov_;                                                                        \
      _Pragma("unroll") for (int r_ = 0; r_ < 4; r_++) ov_[r_] = (bf16)(O[c_][r_] * inv_); \
      size_t addr_ = ((size_t)(b * kS + (Q0) + lr)) * (kH * kD) + h * 64 + c_ * 16 + lg * 4; \
      *(bf16x4*)&ob[addr_] = ov_;                                                        \
    }                                                                                    \
  }

__global__ __launch_bounds__(256, 2) void attn_kernel(const bf16* __restrict__ qb,
                                                      const bf16* __restrict__ kb,
                                                      const bf16* __restrict__ vtb,
                                                      bf16* __restrict__ ob) {
  __shared__ bf16 Ks[2][4096];
  __shared__ bf16 Vs[2][4096];
  const int tid = threadIdx.x;
  const int w = tid >> 6, l = tid & 63;
  const int lr = l & 15, lg = l >> 4;
  const int bid = blockIdx.x;
  const int bh = bid & 31;                  // bid%8 keys XCD -> 4 bh per XCD (2MB KV in L2)
  const int p = bid >> 5;                   // 0..15
  const int qtA = 31 - p, qtB = p;          // paired q-tiles: (qtA+1)+(qtB+1)=33 always
  const bf16* qh = qb + (size_t)bh * (kS * kD);
  const bf16* kh = kb + (size_t)bh * (kS * kD);
  const bf16* vh = vtb + (size_t)bh * (kS * kD);
  const int b = bh >> 4, h = bh & 15;

  STAGE(0, 0)
  __syncthreads();
  int cur = 0;

  {  // ---- heavy tile A ----
    const int q0 = qtA * 64 + w * 16;
    const int q = q0 + lr;
    bf16x8 qf[2];
#pragma unroll
    for (int c = 0; c < 2; c++)
      qf[c] = *(const bf16x8*)&qh[(size_t)(q0 + lr) * kD + c * 32 + lg * 8];
    float m_run = 8.0f, lpart = 0.0f;
    f32x4 o[4] = {};
    for (int t = 0; t <= qtA; t++) {
      STAGE(cur ^ 1, (t < qtA) ? (t + 1) * 64 : 0)   // last iter stages B's tile 0
      COMPUTE(cur, (t == qtA), o, m_run, lpart, qf, q, t * 64)
      __syncthreads();
      cur ^= 1;
    }
    EPILOG(o, lpart, q0)
  }

  {  // ---- light tile B ----
    const int q0 = qtB * 64 + w * 16;
    const int q = q0 + lr;
    bf16x8 qf[2];
#pragma unroll
    for (int c = 0; c < 2; c++)
      qf[c] = *(const bf16x8*)&qh[(size_t)(q0 + lr) * kD + c * 32 + lg * 8];
    float m_run = 8.0f, lpart = 0.0f;
    f32x4 o[4] = {};
    for (int t = 0; t <= qtB; t++) {
      if (t < qtB) STAGE(cur ^ 1, (t + 1) * 64)
      COMPUTE(cur, (t == qtB), o, m_run, lpart, qf, q, t * 64)
      __syncthreads();
      cur ^= 1;
    }
    EPILOG(o, lpart, q0)
  }
}

extern "C" void kernel_launch(void* const* d_in, const int* in_sizes, int n_in,
                              void* d_out, int out_size, void* d_ws, size_t ws_size,
                              hipStream_t stream) {
  const float* x  = (const float*)d_in[0];
  const float* wq = (const float*)d_in[1];
  const float* wk = (const float*)d_in[2];
  const float* wv = (const float*)d_in[3];
  const float* wo = (const float*)d_in[4];

  bf16* xb  = (bf16*)d_ws;            // 4M elems each (8 MiB)
  bf16* qb  = xb + (1 << 22);
  bf16* kb  = qb + (1 << 22);
  bf16* vtb = kb + (1 << 22);
  bf16* ab  = vtb + (1 << 22);
  bf16* wqb = ab + (1 << 22);         // 1M elems each (2 MiB)
  bf16* wkb = wqb + (1 << 20);
  bf16* wvb = wkb + (1 << 20);
  bf16* wob = wvb + (1 << 20);

  cast_all_kernel<<<8192, 256, 0, stream>>>(x, wq, wk, wv, wo, xb, wqb, wkb, wvb, wob);
  gemm_qkv<<<768, 256, 0, stream>>>(xb, wqb, wkb, wvb, qb, kb, vtb);
  attn_kernel<<<512, 256, 0, stream>>>(qb, kb, vtb, ab);
  gemm_out<<<dim3(8, 32), 256, 0, stream>>>(ab, wob, (float*)d_out);
}

// Round 6
// 127.875 us; speedup vs baseline: 3.6675x; 1.0387x over previous
//
#include <hip/hip_runtime.h>
#include <cstdint>
#include <cstddef>

typedef __bf16 bf16;
typedef __attribute__((ext_vector_type(8))) __bf16 bf16x8;
typedef __attribute__((ext_vector_type(4))) __bf16 bf16x4;
typedef __attribute__((ext_vector_type(4))) float f32x4;

constexpr int kS = 2048;
constexpr int kH = 16;
constexpr int kD = 64;

__device__ __forceinline__ void gload16(const bf16* g, bf16* l) {
  __builtin_amdgcn_global_load_lds((const __attribute__((address_space(1))) void*)g,
                                   (__attribute__((address_space(3))) void*)l, 16, 0, 0);
}

// ---------------- cast fp32 -> bf16 (x + 4 weights) ----------------
__global__ __launch_bounds__(256) void cast_all_kernel(
    const float* __restrict__ x, const float* __restrict__ wq, const float* __restrict__ wk,
    const float* __restrict__ wv, const float* __restrict__ wo,
    bf16* __restrict__ xb, bf16* __restrict__ wqb, bf16* __restrict__ wkb,
    bf16* __restrict__ wvb, bf16* __restrict__ wob) {
  int idx = blockIdx.x * 256 + threadIdx.x;   // 2M threads, 4 floats each
  const float* src; bf16* dst; int i;
  if (idx < (1 << 20)) { src = x; dst = xb; i = idx << 2; }
  else {
    int r = idx - (1 << 20);
    int t = r >> 18;
    i = (r & ((1 << 18) - 1)) << 2;
    src = (t == 0) ? wq : (t == 1) ? wk : (t == 2) ? wv : wo;
    dst = (t == 0) ? wqb : (t == 1) ? wkb : (t == 2) ? wvb : wob;
  }
  float4 v = *(const float4*)(src + i);
  bf16x4 o;
  o[0] = (bf16)v.x; o[1] = (bf16)v.y; o[2] = (bf16)v.z; o[3] = (bf16)v.w;
  *(bf16x4*)(dst + i) = o;
}

// LDS granule swizzle (both GEMMs): data for logical (row, chunk lg) lives at
// granule row*4 + (lg ^ ((row>>1)&3)). Staged linearly by global_load_lds with
// the inverse (=same) permutation applied to the global source chunk. Read-side
// quad index (lr&1)*4 + (lg^((lr>>1)&3)) covers all 8 bank-quads per 16-lane
// group -> 2-way (data-minimum) instead of 8-way conflicts.

#define GSTAGE(BUF, KT)                                    \
  gload16(aP0 + (KT), &As[BUF][(w * 64 + l) * 8]);         \
  gload16(aP1 + (KT), &As[BUF][((4 + w) * 64 + l) * 8]);   \
  gload16(bP0 + (KT), &Bs[BUF][(w * 64 + l) * 8]);         \
  gload16(bP1 + (KT), &Bs[BUF][((4 + w) * 64 + l) * 8]);

// ---------------- fused QKV GEMM + RoPE + layout transforms ----------------
__global__ __launch_bounds__(256) void gemm_qkv(const bf16* __restrict__ A,
                                                const bf16* __restrict__ wq,
                                                const bf16* __restrict__ wk,
                                                const bf16* __restrict__ wv,
                                                bf16* __restrict__ qo,
                                                bf16* __restrict__ ko,
                                                bf16* __restrict__ vto) {
  __shared__ bf16 As[2][128 * 32];
  __shared__ bf16 Bs[2][128 * 32];
  const int tid = threadIdx.x;
  const int w = tid >> 6, l = tid & 63;
  const int wr = w >> 1, wc = w & 1;
  const int lr = l & 15, lg = l >> 4;

  // XCD-aware remap of 768 blocks (768 % 8 == 0 -> bijective)
  const int fid = (blockIdx.x & 7) * 96 + (blockIdx.x >> 3);
  const int mblk = fid & 31;            // 0..31
  const int ntile = fid >> 5;           // 0..23
  const int which = ntile >> 3;         // 0=q 1=k 2=v
  const int m0 = mblk * 128;
  const int n0 = (ntile & 7) * 128;
  const bf16* Bw = (which == 0) ? wq : (which == 1) ? wk : wv;

  const int srow = l >> 2;
  const int skcol = ((l & 3) ^ ((l >> 3) & 3)) << 3;   // swizzled source chunk
  const int K = 1024;

  const bf16* aP0 = A + (size_t)(m0 + w * 16 + srow) * K + skcol;
  const bf16* aP1 = A + (size_t)(m0 + 64 + w * 16 + srow) * K + skcol;
  const bf16* bP0 = Bw + (size_t)(n0 + w * 16 + srow) * K + skcol;
  const bf16* bP1 = Bw + (size_t)(n0 + 64 + w * 16 + srow) * K + skcol;

  f32x4 acc[4][4] = {};
  const int ca = (lg ^ ((lr >> 1) & 3)) * 8;           // swizzled read chunk

  GSTAGE(0, 0)
  __syncthreads();
  int cur = 0;
  for (int kt = 0; kt < K; kt += 32) {
    if (kt + 32 < K) { GSTAGE(cur ^ 1, kt + 32) }
    bf16x8 af[4], bfg[4];
#pragma unroll
    for (int mi = 0; mi < 4; mi++)
      af[mi] = *(const bf16x8*)&As[cur][(wr * 64 + mi * 16 + lr) * 32 + ca];
#pragma unroll
    for (int ni = 0; ni < 4; ni++)
      bfg[ni] = *(const bf16x8*)&Bs[cur][(wc * 64 + ni * 16 + lr) * 32 + ca];
    __builtin_amdgcn_s_setprio(1);
#pragma unroll
    for (int mi = 0; mi < 4; mi++)
#pragma unroll
      for (int ni = 0; ni < 4; ni++)
        acc[mi][ni] = __builtin_amdgcn_mfma_f32_16x16x32_bf16(af[mi], bfg[ni], acc[mi][ni], 0, 0, 0);
    __builtin_amdgcn_s_setprio(0);
    __syncthreads();
    cur ^= 1;
  }

  float invf_[4];
#pragma unroll
  for (int ni = 0; ni < 4; ni++) {
    int d31 = ((n0 + wc * 64 + ni * 16 + lr) & 63) & 31;
    invf_[ni] = exp2f((float)d31 * -0.41524100480466348f);   // 10000^(-(d&31)/32)
  }

#pragma unroll
  for (int mi = 0; mi < 4; mi++) {
#pragma unroll
    for (int ni = 0; ni < 4; ni++) {
#pragma unroll
      for (int r = 0; r < 4; r++) {
        const int m = m0 + wr * 64 + mi * 16 + lg * 4 + r;   // token index
        const int n = n0 + wc * 64 + ni * 16 + lr;           // emb index (h*64+d)
        float v = acc[mi][ni][r];
        const int st = m & 2047;                              // seq position
        const size_t bh = (size_t)(m >> 11) * kH + (n >> 6);
        if (which < 2) {
          float vp = __shfl_xor(v, 1);
          const int d = n & 63;
          float th = (float)st * invf_[ni];
          float sth = __sinf(th), cth = __cosf(th);
          float rv = v * cth + ((d & 1) ? vp : -vp) * sth;
          bf16* dst = which ? ko : qo;                       // [B,H,S,D]
          dst[((bh << 11) + st) * kD + (n & 63)] = (bf16)rv;
        } else {                                             // [B,H,D,S] permuted
          int pos = (st & ~31) | (((st >> 2) & 3) << 3) | (((st >> 4) & 1) << 2) | (st & 3);
          vto[((bh * kD + (n & 63)) << 11) + pos] = (bf16)v;
        }
      }
    }
  }
}

// ---------------- final GEMM C = A @ Wo^T, fp32 out ----------------
__global__ __launch_bounds__(256) void gemm_out(const bf16* __restrict__ A,
                                                const bf16* __restrict__ Bw,
                                                float* __restrict__ Cout) {
  __shared__ bf16 As[2][128 * 32];
  __shared__ bf16 Bs[2][128 * 32];
  const int tid = threadIdx.x;
  const int w = tid >> 6, l = tid & 63;
  const int wr = w >> 1, wc = w & 1;
  const int lr = l & 15, lg = l >> 4;
  const int m0 = blockIdx.y * 128, n0 = blockIdx.x * 128;
  const int K = 1024, N = 1024;

  const int srow = l >> 2;
  const int skcol = ((l & 3) ^ ((l >> 3) & 3)) << 3;

  const bf16* aP0 = A + (size_t)(m0 + w * 16 + srow) * K + skcol;
  const bf16* aP1 = A + (size_t)(m0 + 64 + w * 16 + srow) * K + skcol;
  const bf16* bP0 = Bw + (size_t)(n0 + w * 16 + srow) * K + skcol;
  const bf16* bP1 = Bw + (size_t)(n0 + 64 + w * 16 + srow) * K + skcol;

  f32x4 acc[4][4] = {};
  const int ca = (lg ^ ((lr >> 1) & 3)) * 8;

  GSTAGE(0, 0)
  __syncthreads();
  int cur = 0;
  for (int kt = 0; kt < K; kt += 32) {
    if (kt + 32 < K) { GSTAGE(cur ^ 1, kt + 32) }
    bf16x8 af[4], bfg[4];
#pragma unroll
    for (int mi = 0; mi < 4; mi++)
      af[mi] = *(const bf16x8*)&As[cur][(wr * 64 + mi * 16 + lr) * 32 + ca];
#pragma unroll
    for (int ni = 0; ni < 4; ni++)
      bfg[ni] = *(const bf16x8*)&Bs[cur][(wc * 64 + ni * 16 + lr) * 32 + ca];
    __builtin_amdgcn_s_setprio(1);
#pragma unroll
    for (int mi = 0; mi < 4; mi++)
#pragma unroll
      for (int ni = 0; ni < 4; ni++)
        acc[mi][ni] = __builtin_amdgcn_mfma_f32_16x16x32_bf16(af[mi], bfg[ni], acc[mi][ni], 0, 0, 0);
    __builtin_amdgcn_s_setprio(0);
    __syncthreads();
    cur ^= 1;
  }

#pragma unroll
  for (int mi = 0; mi < 4; mi++)
#pragma unroll
    for (int ni = 0; ni < 4; ni++)
#pragma unroll
      for (int r = 0; r < 4; r++) {
        const int m = m0 + wr * 64 + mi * 16 + lg * 4 + r;
        const int n = n0 + wc * 64 + ni * 16 + lr;
        Cout[(size_t)m * N + n] = acc[mi][ni][r];
      }
}

// ---------------- flash attention, causal, LDS-staged, pair-balanced ----------------
// Block = (bh, pair p): processes q-tile (31-p) then q-tile p -> 33 kv-tile
// iterations per block, uniform. 512 blocks, 256 threads.
// Per kv-tile: K,V (8KB each) staged to LDS in exact fragment order via
// global_load_lds (4 issues/wave), double-buffered, one barrier per tile.
// Swapped QK^T keeps softmax per-lane; defer-max skips wave reductions.
// V comes pre-permuted ([B,H,D,S] with 32-chunk MFMA permutation) so V
// fragments are single b128 reads.

#define STAGE(BUF, KV0)                                                                  \
  {                                                                                      \
    const bf16* kg_ = kh + (size_t)((KV0) + w * 16 + lr) * 64 + lg * 8;                  \
    gload16(kg_,      &Ks[BUF][(w * 2 + 0) * 512 + l * 8]);                              \
    gload16(kg_ + 32, &Ks[BUF][(w * 2 + 1) * 512 + l * 8]);                              \
    const bf16* vg_ = vh + (size_t)(w * 16 + lr) * 2048 + (KV0) + lg * 8;                \
    gload16(vg_,      &Vs[BUF][(w * 2 + 0) * 512 + l * 8]);                              \
    gload16(vg_ + 32, &Vs[BUF][(w * 2 + 1) * 512 + l * 8]);                              \
  }

#define COMPUTE(BUF, DIAG, O, MRUN, LPART, QF, QROW, KVB)                                \
  {                                                                                      \
    bf16x8 kf_[4][2], vf_[4][2];                                                         \
    _Pragma("unroll") for (int s_ = 0; s_ < 4; s_++)                                     \
      _Pragma("unroll") for (int c_ = 0; c_ < 2; c_++)                                   \
        kf_[s_][c_] = *(const bf16x8*)&Ks[BUF][(s_ * 2 + c_) * 512 + l * 8];             \
    _Pragma("unroll") for (int c_ = 0; c_ < 4; c_++)                                     \
      _Pragma("unroll") for (int f_ = 0; f_ < 2; f_++)                                   \
        vf_[c_][f_] = *(const bf16x8*)&Vs[BUF][(c_ * 2 + f_) * 512 + l * 8];             \
    f32x4 sa_[4] = {};                                                                   \
    __builtin_amdgcn_s_setprio(1);                                                       \
    _Pragma("unroll") for (int s_ = 0; s_ < 4; s_++) {                                   \
      sa_[s_] = __builtin_amdgcn_mfma_f32_16x16x32_bf16(kf_[s_][0], QF[0], sa_[s_], 0, 0, 0); \
      sa_[s_] = __builtin_amdgcn_mfma_f32_16x16x32_bf16(kf_[s_][1], QF[1], sa_[s_], 0, 0, 0); \
    }                                                                                    \
    __builtin_amdgcn_s_setprio(0);                                                       \
    float sc_[4][4];                                                                     \
    float tml_ = -1e30f;                                                                 \
    _Pragma("unroll") for (int s_ = 0; s_ < 4; s_++)                                     \
      _Pragma("unroll") for (int r_ = 0; r_ < 4; r_++) {                                 \
        float v_ = sa_[s_][r_] * 0.125f;                                                 \
        if (DIAG) {                                                                      \
          int kk_ = (KVB) + s_ * 16 + lg * 4 + r_;                                       \
          v_ = (kk_ <= (QROW)) ? v_ : -1e30f;                                            \
        }                                                                                \
        sc_[s_][r_] = v_;                                                                \
        tml_ = fmaxf(tml_, v_);                                                          \
      }                                                                                  \
    if (__any(tml_ > MRUN + 20.0f)) {                                                    \
      float tm_ = tml_;                                                                  \
      tm_ = fmaxf(tm_, __shfl_xor(tm_, 16));                                             \
      tm_ = fmaxf(tm_, __shfl_xor(tm_, 32));                                             \
      tm_ = fmaxf(tm_, MRUN);                                                            \
      float f_ = __expf(MRUN - tm_);                                                     \
      _Pragma("unroll") for (int c_ = 0; c_ < 4; c_++) O[c_] *= f_;                      \
      LPART *= f_;                                                                       \
      MRUN = tm_;                                                                        \
    }                                                                                    \
    bf16x8 pf_[2];                                                                       \
    float ts_ = 0.0f;                                                                    \
    _Pragma("unroll") for (int s_ = 0; s_ < 4; s_++)                                     \
      _Pragma("unroll") for (int r_ = 0; r_ < 4; r_++) {                                 \
        float e_ = __expf(sc_[s_][r_] - MRUN);                                           \
        ts_ += e_;                                                                       \
        pf_[s_ >> 1][(s_ & 1) * 4 + r_] = (bf16)e_;                                      \
      }                                                                                  \
    LPART += ts_;                                                                        \
    __builtin_amdgcn_s_setprio(1);                                                       \
    _Pragma("unroll") for (int c_ = 0; c_ < 4; c_++) {                                   \
      O[c_] = __builtin_amdgcn_mfma_f32_16x16x32_bf16(vf_[c_][0], pf_[0], O[c_], 0, 0, 0); \
      O[c_] = __builtin_amdgcn_mfma_f32_16x16x32_bf16(vf_[c_][1], pf_[1], O[c_], 0, 0, 0); \
    }                                                                                    \
    __builtin_amdgcn_s_setprio(0);                                                       \
  }

#define EPILOG(O, LPART, Q0)                                                             \
  {                                                                                      \
    float lt_ = LPART;                                                                   \
    lt_ += __shfl_xor(lt_, 16);                                                          \
    lt_ += __shfl_xor(lt_, 32);                                                          \
    const float inv_ = 1.0f / lt_;                                                       \
    _Pragma("unroll") for (int c_ = 0; c_ < 4; c_++) {                                   \
      bf16x4 ov_;                                                                        \
      _Pragma("unroll") for (int r_ = 0; r_ < 4; r_++) ov_[r_] = (bf16)(O[c_][r_] * inv_); \
      size_t addr_ = ((size_t)(b * kS + (Q0) + lr)) * (kH * kD) + h * 64 + c_ * 16 + lg * 4; \
      *(bf16x4*)&ob[addr_] = ov_;                                                        \
    }                                                                                    \
  }

__global__ __launch_bounds__(256, 2) void attn_kernel(const bf16* __restrict__ qb,
                                                      const bf16* __restrict__ kb,
                                                      const bf16* __restrict__ vtb,
                                                      bf16* __restrict__ ob) {
  __shared__ bf16 Ks[2][4096];
  __shared__ bf16 Vs[2][4096];
  const int tid = threadIdx.x;
  const int w = tid >> 6, l = tid & 63;
  const int lr = l & 15, lg = l >> 4;
  const int bid = blockIdx.x;
  const int bh = bid & 31;                  // bid%8 keys XCD -> 4 bh per XCD (2MB KV in L2)
  const int p = bid >> 5;                   // 0..15
  const int qtA = 31 - p, qtB = p;          // paired q-tiles: (qtA+1)+(qtB+1)=33 always
  const bf16* qh = qb + (size_t)bh * (kS * kD);
  const bf16* kh = kb + (size_t)bh * (kS * kD);
  const bf16* vh = vtb + (size_t)bh * (kS * kD);
  const int b = bh >> 4, h = bh & 15;

  STAGE(0, 0)
  __syncthreads();
  int cur = 0;

  {  // ---- heavy tile A ----
    const int q0 = qtA * 64 + w * 16;
    const int q = q0 + lr;
    bf16x8 qf[2];
#pragma unroll
    for (int c = 0; c < 2; c++)
      qf[c] = *(const bf16x8*)&qh[(size_t)(q0 + lr) * kD + c * 32 + lg * 8];
    float m_run = 8.0f, lpart = 0.0f;
    f32x4 o[4] = {};
    for (int t = 0; t <= qtA; t++) {
      STAGE(cur ^ 1, (t < qtA) ? (t + 1) * 64 : 0)   // last iter stages B's tile 0
      COMPUTE(cur, (t == qtA), o, m_run, lpart, qf, q, t * 64)
      __syncthreads();
      cur ^= 1;
    }
    EPILOG(o, lpart, q0)
  }

  {  // ---- light tile B ----
    const int q0 = qtB * 64 + w * 16;
    const int q = q0 + lr;
    bf16x8 qf[2];
#pragma unroll
    for (int c = 0; c < 2; c++)
      qf[c] = *(const bf16x8*)&qh[(size_t)(q0 + lr) * kD + c * 32 + lg * 8];
    float m_run = 8.0f, lpart = 0.0f;
    f32x4 o[4] = {};
    for (int t = 0; t <= qtB; t++) {
      if (t < qtB) STAGE(cur ^ 1, (t + 1) * 64)
      COMPUTE(cur, (t == qtB), o, m_run, lpart, qf, q, t * 64)
      __syncthreads();
      cur ^= 1;
    }
    EPILOG(o, lpart, q0)
  }
}

extern "C" void kernel_launch(void* const* d_in, const int* in_sizes, int n_in,
                              void* d_out, int out_size, void* d_ws, size_t ws_size,
                              hipStream_t stream) {
  const float* x  = (const float*)d_in[0];
  const float* wq = (const float*)d_in[1];
  const float* wk = (const float*)d_in[2];
  const float* wv = (const float*)d_in[3];
  const float* wo = (const float*)d_in[4];

  bf16* xb  = (bf16*)d_ws;            // 4M elems each (8 MiB)
  bf16* qb  = xb + (1 << 22);
  bf16* kb  = qb + (1 << 22);
  bf16* vtb = kb + (1 << 22);
  bf16* ab  = vtb + (1 << 22);
  bf16* wqb = ab + (1 << 22);         // 1M elems each (2 MiB)
  bf16* wkb = wqb + (1 << 20);
  bf16* wvb = wkb + (1 << 20);
  bf16* wob = wvb + (1 << 20);

  cast_all_kernel<<<8192, 256, 0, stream>>>(x, wq, wk, wv, wo, xb, wqb, wkb, wvb, wob);
  gemm_qkv<<<768, 256, 0, stream>>>(xb, wqb, wkb, wvb, qb, kb, vtb);
  attn_kernel<<<512, 256, 0, stream>>>(qb, kb, vtb, ab);
  gemm_out<<<dim3(8, 32), 256, 0, stream>>>(ab, wob, (float*)d_out);
}